// Round 1
// baseline (598.990 us; speedup 1.0000x reference)
//
#include <hip/hip_runtime.h>

#define N_NODES   50000
#define N_EDGES   800000
#define DIM       64
#define NUM_GRAPHS 512
#define EPS       1e-5f

// ---------------------------------------------------------------- zero init
__global__ void k_zero(int* __restrict__ deg, float* __restrict__ sums2,
                       float* __restrict__ sums3, float* __restrict__ pooled) {
    int i = blockIdx.x * 256 + threadIdx.x;
    if (i < N_NODES) deg[i] = 0;
    if (i < 128) { sums2[i] = 0.f; sums3[i] = 0.f; }
    if (i < NUM_GRAPHS * DIM) pooled[i] = 0.f;
}

// ---------------------------------------------------------------- degree count
__global__ void k_count(const int* __restrict__ dst, int* __restrict__ deg) {
    int i = blockIdx.x * 256 + threadIdx.x;
    if (i < N_EDGES) atomicAdd(&deg[dst[i]], 1);
}

// ---------------------------------------------------------------- prefix scan (single block)
#define SCAN_T 1024
#define CHUNK  49   // ceil(50000/1024)
__global__ void __launch_bounds__(1024)
k_scan(const int* __restrict__ deg, int* __restrict__ off,
       int* __restrict__ cursor, float* __restrict__ inv_deg) {
    __shared__ int part[SCAN_T];
    int t = threadIdx.x;
    int lo = t * CHUNK;
    int hi = min(lo + CHUNK, N_NODES);
    int s = 0;
    for (int i = lo; i < hi; ++i) s += deg[i];
    part[t] = s;
    __syncthreads();
    // inclusive Hillis-Steele scan
    for (int d = 1; d < SCAN_T; d <<= 1) {
        int v = part[t];
        int u = (t >= d) ? part[t - d] : 0;
        __syncthreads();
        part[t] = v + u;
        __syncthreads();
    }
    int run = (t > 0) ? part[t - 1] : 0;  // exclusive prefix of this chunk
    for (int i = lo; i < hi; ++i) {
        int d = deg[i];
        off[i] = run;
        cursor[i] = run;
        inv_deg[i] = 1.0f / (float)max(d, 1);
        run += d;
    }
    if (t == SCAN_T - 1) off[N_NODES] = run;
}

// ---------------------------------------------------------------- CSR scatter
__global__ void k_scatter(const int* __restrict__ src, const int* __restrict__ dst,
                          int* __restrict__ cursor, int* __restrict__ csr_src) {
    int i = blockIdx.x * 256 + threadIdx.x;
    if (i < N_EDGES) {
        int p = atomicAdd(&cursor[dst[i]], 1);
        csr_src[p] = src[i];
    }
}

// ---------------------------------------------------------------- dual GEMM: xs = BN(x)@Ws + b ; xn = BN(x)@Wn
template<bool BN>
__global__ void __launch_bounds__(256)
k_gemm(const float* __restrict__ x, const float* __restrict__ Ws,
       const float* __restrict__ Wn, const float* __restrict__ bias,
       const float* __restrict__ bn_a, const float* __restrict__ bn_c,
       float* __restrict__ xs, float* __restrict__ xn) {
    __shared__ float sWs[DIM * DIM];
    __shared__ float sWn[DIM * DIM];
    __shared__ float sX[16][DIM];
    __shared__ float sb[DIM], sA[DIM], sC[DIM];
    int tid = threadIdx.x;
    for (int i = tid; i < DIM * DIM; i += 256) { sWs[i] = Ws[i]; sWn[i] = Wn[i]; }
    if (tid < DIM) {
        sb[tid] = bias[tid];
        if constexpr (BN) { sA[tid] = bn_a[tid]; sC[tid] = bn_c[tid]; }
        else              { sA[tid] = 1.f;       sC[tid] = 0.f;       }
    }
    __syncthreads();
    int rowBase = blockIdx.x * 16;
    for (int i = tid; i < 16 * DIM; i += 256) {
        int r = i >> 6, c = i & 63;
        int gr = rowBase + r;
        float v = (gr < N_NODES) ? x[gr * DIM + c] : 0.f;
        sX[r][c] = fmaf(v, sA[c], sC[c]);
    }
    __syncthreads();

    int lane = tid & 63, w = tid >> 6;     // lane = output column, w = row group
    float b = sb[lane];
    float s0 = b, s1 = b, s2 = b, s3 = b;
    float n0 = 0.f, n1 = 0.f, n2 = 0.f, n3 = 0.f;
#pragma unroll
    for (int k = 0; k < DIM; ++k) {
        float ws = sWs[k * DIM + lane];
        float wn = sWn[k * DIM + lane];
        float x0 = sX[w * 4 + 0][k];
        float x1 = sX[w * 4 + 1][k];
        float x2 = sX[w * 4 + 2][k];
        float x3 = sX[w * 4 + 3][k];
        s0 = fmaf(x0, ws, s0); n0 = fmaf(x0, wn, n0);
        s1 = fmaf(x1, ws, s1); n1 = fmaf(x1, wn, n1);
        s2 = fmaf(x2, ws, s2); n2 = fmaf(x2, wn, n2);
        s3 = fmaf(x3, ws, s3); n3 = fmaf(x3, wn, n3);
    }
    int r0 = rowBase + w * 4;
    if (r0 + 0 < N_NODES) { xs[(r0 + 0) * DIM + lane] = s0; xn[(r0 + 0) * DIM + lane] = n0; }
    if (r0 + 1 < N_NODES) { xs[(r0 + 1) * DIM + lane] = s1; xn[(r0 + 1) * DIM + lane] = n1; }
    if (r0 + 2 < N_NODES) { xs[(r0 + 2) * DIM + lane] = s2; xn[(r0 + 2) * DIM + lane] = n2; }
    if (r0 + 3 < N_NODES) { xs[(r0 + 3) * DIM + lane] = s3; xn[(r0 + 3) * DIM + lane] = n3; }
}

// ---------------------------------------------------------------- aggregate: h = relu(xs + inv_deg * sum_{src} xn[src])
template<bool POOL>
__global__ void __launch_bounds__(256)
k_agg(const float* __restrict__ xs, const float* __restrict__ xn,
      const int* __restrict__ off, const int* __restrict__ csr_src,
      const float* __restrict__ inv_deg, const int* __restrict__ gind,
      float* __restrict__ h, float* __restrict__ pooled) {
    int lane = threadIdx.x & 63, w = threadIdx.x >> 6;
    int row = blockIdx.x * 4 + w;
    if (row >= N_NODES) return;
    int jb = off[row], je = off[row + 1];
    float acc = 0.f;
    int j = jb;
    for (; j + 4 <= je; j += 4) {
        int i0 = csr_src[j], i1 = csr_src[j + 1], i2 = csr_src[j + 2], i3 = csr_src[j + 3];
        float v0 = xn[i0 * DIM + lane];
        float v1 = xn[i1 * DIM + lane];
        float v2 = xn[i2 * DIM + lane];
        float v3 = xn[i3 * DIM + lane];
        acc += (v0 + v1) + (v2 + v3);
    }
    for (; j < je; ++j) acc += xn[csr_src[j] * DIM + lane];
    float val = fmaf(acc, inv_deg[row], xs[row * DIM + lane]);
    val = fmaxf(val, 0.f);
    h[row * DIM + lane] = val;
    if constexpr (POOL) {
        int g = gind[row];
        atomicAdd(&pooled[g * DIM + lane], val);
    }
}

// ---------------------------------------------------------------- BN stats (sum, sumsq per channel)
__global__ void __launch_bounds__(256)
k_stats(const float* __restrict__ h, float* __restrict__ sums) {
    int lane = threadIdx.x & 63, w = threadIdx.x >> 6;
    float s = 0.f, q = 0.f;
    for (int r = blockIdx.x * 4 + w; r < N_NODES; r += gridDim.x * 4) {
        float v = h[r * DIM + lane];
        s += v;
        q = fmaf(v, v, q);
    }
    __shared__ float sS[4][DIM], sQ[4][DIM];
    sS[w][lane] = s; sQ[w][lane] = q;
    __syncthreads();
    if (w == 0) {
        float ts = sS[0][lane] + sS[1][lane] + sS[2][lane] + sS[3][lane];
        float tq = sQ[0][lane] + sQ[1][lane] + sQ[2][lane] + sQ[3][lane];
        atomicAdd(&sums[lane], ts);
        atomicAdd(&sums[DIM + lane], tq);
    }
}

// ---------------------------------------------------------------- BN finalize: a = g*rsqrt(var+eps), c = be - mean*a
__global__ void k_bnfin(const float* __restrict__ sums, const float* __restrict__ g,
                        const float* __restrict__ be, float* __restrict__ a,
                        float* __restrict__ c) {
    int t = threadIdx.x;  // 64 threads
    float m = sums[t] * (1.0f / N_NODES);
    float q = sums[DIM + t] * (1.0f / N_NODES);
    float v = q - m * m;
    float inv = 1.0f / sqrtf(v + EPS);
    float av = g[t] * inv;
    a[t] = av;
    c[t] = be[t] - m * av;
}

// ---------------------------------------------------------------- MLP head (one block per graph)
__global__ void __launch_bounds__(128)
k_mlp(const float* __restrict__ pooled,
      const float* __restrict__ W1, const float* __restrict__ b1,
      const float* __restrict__ W2, const float* __restrict__ b2,
      const float* __restrict__ W3, const float* __restrict__ b3,
      float* __restrict__ out) {
    __shared__ float sp[64], s1[128], s2[64];
    int g = blockIdx.x, t = threadIdx.x;
    if (t < 64) sp[t] = pooled[g * 64 + t];
    __syncthreads();
    {
        float acc = b1[t];
#pragma unroll
        for (int k = 0; k < 64; ++k) acc = fmaf(sp[k], W1[k * 128 + t], acc);
        s1[t] = fmaxf(acc, 0.f);
    }
    __syncthreads();
    if (t < 64) {
        float acc = b2[t];
#pragma unroll
        for (int k = 0; k < 128; ++k) acc = fmaf(s1[k], W2[k * 64 + t], acc);
        s2[t] = fmaxf(acc, 0.f);
    }
    __syncthreads();
    if (t < 10) {
        float acc = b3[t];
#pragma unroll
        for (int k = 0; k < 64; ++k) acc = fmaf(s2[k], W3[k * 10 + t], acc);
        out[g * 10 + t] = acc;
    }
}

// ---------------------------------------------------------------- launch
extern "C" void kernel_launch(void* const* d_in, const int* in_sizes, int n_in,
                              void* d_out, int out_size, void* d_ws, size_t ws_size,
                              hipStream_t stream) {
    const float* x0   = (const float*)d_in[0];
    const int* e_src  = (const int*)d_in[1];
    const int* e_dst  = (const int*)d_in[2];
    const int* gind   = (const int*)d_in[3];
    // d_in[4] = labels (unused)
    const float* Ws1 = (const float*)d_in[5],  *Wn1 = (const float*)d_in[6],  *b1 = (const float*)d_in[7];
    const float* Ws2 = (const float*)d_in[8],  *Wn2 = (const float*)d_in[9],  *b2 = (const float*)d_in[10];
    const float* Ws3 = (const float*)d_in[11], *Wn3 = (const float*)d_in[12], *b3 = (const float*)d_in[13];
    const float* g2  = (const float*)d_in[14], *be2 = (const float*)d_in[15];
    const float* g3  = (const float*)d_in[16], *be3 = (const float*)d_in[17];
    const float* fcW1 = (const float*)d_in[18], *fcb1 = (const float*)d_in[19];
    const float* fcW2 = (const float*)d_in[20], *fcb2 = (const float*)d_in[21];
    const float* fcW3 = (const float*)d_in[22], *fcb3 = (const float*)d_in[23];
    float* out = (float*)d_out;

    char* p = (char*)d_ws;
    auto carve = [&](size_t bytes) { void* r = (void*)p; p += (bytes + 255) & ~(size_t)255; return r; };
    int*   deg     = (int*)  carve(N_NODES * 4);
    int*   off     = (int*)  carve((N_NODES + 1) * 4);
    int*   cursor  = (int*)  carve(N_NODES * 4);
    int*   csr_src = (int*)  carve(N_EDGES * 4);
    float* invd    = (float*)carve(N_NODES * 4);
    float* sums2   = (float*)carve(128 * 4);
    float* sums3   = (float*)carve(128 * 4);
    float* a2      = (float*)carve(64 * 4);
    float* c2      = (float*)carve(64 * 4);
    float* a3      = (float*)carve(64 * 4);
    float* c3      = (float*)carve(64 * 4);
    float* pooled  = (float*)carve(NUM_GRAPHS * DIM * 4);
    float* bufH    = (float*)carve((size_t)N_NODES * DIM * 4);
    float* bufXS   = (float*)carve((size_t)N_NODES * DIM * 4);
    float* bufXN   = (float*)carve((size_t)N_NODES * DIM * 4);

    const int EB = (N_EDGES + 255) / 256;           // 3125
    const int GB = (N_NODES + 15) / 16;             // 3125 (gemm: 16 rows/block)
    const int AB = (N_NODES + 3) / 4;               // 12500 (agg: 4 rows/block)

    k_zero<<<(N_NODES + 255) / 256, 256, 0, stream>>>(deg, sums2, sums3, pooled);
    k_count<<<EB, 256, 0, stream>>>(e_dst, deg);
    k_scan<<<1, SCAN_T, 0, stream>>>(deg, off, cursor, invd);
    k_scatter<<<EB, 256, 0, stream>>>(e_src, e_dst, cursor, csr_src);

    // Layer 1 (no BN on input)
    k_gemm<false><<<GB, 256, 0, stream>>>(x0, Ws1, Wn1, b1, nullptr, nullptr, bufXS, bufXN);
    k_agg<false><<<AB, 256, 0, stream>>>(bufXS, bufXN, off, csr_src, invd, nullptr, bufH, nullptr);

    // BN2 stats + Layer 2
    k_stats<<<120, 256, 0, stream>>>(bufH, sums2);
    k_bnfin<<<1, 64, 0, stream>>>(sums2, g2, be2, a2, c2);
    k_gemm<true><<<GB, 256, 0, stream>>>(bufH, Ws2, Wn2, b2, a2, c2, bufXS, bufXN);
    k_agg<false><<<AB, 256, 0, stream>>>(bufXS, bufXN, off, csr_src, invd, nullptr, bufH, nullptr);

    // BN3 stats + Layer 3 (fused pooling)
    k_stats<<<120, 256, 0, stream>>>(bufH, sums3);
    k_bnfin<<<1, 64, 0, stream>>>(sums3, g3, be3, a3, c3);
    k_gemm<true><<<GB, 256, 0, stream>>>(bufH, Ws3, Wn3, b3, a3, c3, bufXS, bufXN);
    k_agg<true><<<AB, 256, 0, stream>>>(bufXS, bufXN, off, csr_src, invd, gind, bufH, pooled);

    // MLP head
    k_mlp<<<NUM_GRAPHS, 128, 0, stream>>>(pooled, fcW1, fcb1, fcW2, fcb2, fcW3, fcb3, out);
}

// Round 2
// 467.048 us; speedup vs baseline: 1.2825x; 1.2825x over previous
//
#include <hip/hip_runtime.h>

#define N_NODES   50000
#define N_EDGES   800000
#define DIM       64
#define NUM_GRAPHS 512
#define EPS       1e-5f

#define SB   1024
#define NSB  ((N_NODES + SB - 1) / SB)   // 49 scan blocks

// ---------------------------------------------------------------- zero init
__global__ void k_zero(int* __restrict__ deg, float* __restrict__ sums2,
                       float* __restrict__ sums3, float* __restrict__ pooled) {
    int i = blockIdx.x * 256 + threadIdx.x;
    if (i < N_NODES) deg[i] = 0;
    if (i < 128) { sums2[i] = 0.f; sums3[i] = 0.f; }
    if (i < NUM_GRAPHS * DIM) pooled[i] = 0.f;
}

// ---------------------------------------------------------------- degree count
__global__ void k_count(const int* __restrict__ dst, int* __restrict__ deg) {
    int i = blockIdx.x * 256 + threadIdx.x;
    if (i < N_EDGES) atomicAdd(&deg[dst[i]], 1);
}

// ---------------------------------------------------------------- scan phase 1: per-block sums
__global__ void __launch_bounds__(1024)
k_scan1(const int* __restrict__ deg, int* __restrict__ bsum) {
    __shared__ int red[16];
    int t = threadIdx.x;
    int i = blockIdx.x * SB + t;
    int v = (i < N_NODES) ? deg[i] : 0;
#pragma unroll
    for (int d = 32; d; d >>= 1) v += __shfl_down(v, d, 64);
    if ((t & 63) == 0) red[t >> 6] = v;
    __syncthreads();
    if (t < 16) {
        int s = red[t];
#pragma unroll
        for (int d = 8; d; d >>= 1) s += __shfl_down(s, d, 16);
        if (t == 0) bsum[blockIdx.x] = s;
    }
}

// ---------------------------------------------------------------- scan phase 2: scan of 49 block sums (1 wave)
__global__ void k_scan2(const int* __restrict__ bsum, int* __restrict__ boff) {
    int t = threadIdx.x;   // 64 threads
    int v = (t < NSB) ? bsum[t] : 0;
    int orig = v;
#pragma unroll
    for (int d = 1; d < 64; d <<= 1) {
        int u = __shfl_up(v, d, 64);
        if (t >= d) v += u;
    }
    if (t < NSB) boff[t] = v - orig;   // exclusive prefix
}

// ---------------------------------------------------------------- scan phase 3: full exclusive scan, write off/cursor/invd
__global__ void __launch_bounds__(1024)
k_scan3(const int* __restrict__ deg, const int* __restrict__ boff,
        int* __restrict__ off, int* __restrict__ cursor, float* __restrict__ invd) {
    __shared__ int wsum[16];
    int t = threadIdx.x, lane = t & 63, w = t >> 6;
    int i = blockIdx.x * SB + t;
    int d = (i < N_NODES) ? deg[i] : 0;
    int v = d;
#pragma unroll
    for (int s = 1; s < 64; s <<= 1) {
        int u = __shfl_up(v, s, 64);
        if (lane >= s) v += u;
    }
    if (lane == 63) wsum[w] = v;
    __syncthreads();
    if (t < 16) {
        int x = wsum[t];
#pragma unroll
        for (int s = 1; s < 16; s <<= 1) {
            int u = __shfl_up(x, s, 16);
            if (t >= s) x += u;
        }
        wsum[t] = x;   // inclusive across waves (lockstep within wave 0)
    }
    __syncthreads();
    if (i < N_NODES) {
        int ex = boff[blockIdx.x] + ((w > 0) ? wsum[w - 1] : 0) + v - d;
        off[i] = ex;
        cursor[i] = ex;
        invd[i] = 1.0f / (float)max(d, 1);
        if (i == N_NODES - 1) off[N_NODES] = ex + d;
    }
}

// ---------------------------------------------------------------- CSR scatter
__global__ void k_scatter(const int* __restrict__ src, const int* __restrict__ dst,
                          int* __restrict__ cursor, int* __restrict__ csr_src) {
    int i = blockIdx.x * 256 + threadIdx.x;
    if (i < N_EDGES) {
        int p = atomicAdd(&cursor[dst[i]], 1);
        csr_src[p] = src[i];
    }
}

// ---------------------------------------------------------------- dual GEMM: xs = BN(x)@Ws + b ; xn = BN(x)@Wn
template<bool BN>
__global__ void __launch_bounds__(256)
k_gemm(const float* __restrict__ x, const float* __restrict__ Ws,
       const float* __restrict__ Wn, const float* __restrict__ bias,
       const float* __restrict__ bn_a, const float* __restrict__ bn_c,
       float* __restrict__ xs, float* __restrict__ xn) {
    __shared__ float sWs[DIM * DIM];
    __shared__ float sWn[DIM * DIM];
    __shared__ float sX[16][DIM];
    __shared__ float sb[DIM], sA[DIM], sC[DIM];
    int tid = threadIdx.x;
    for (int i = tid; i < DIM * DIM; i += 256) { sWs[i] = Ws[i]; sWn[i] = Wn[i]; }
    if (tid < DIM) {
        sb[tid] = bias[tid];
        if constexpr (BN) { sA[tid] = bn_a[tid]; sC[tid] = bn_c[tid]; }
        else              { sA[tid] = 1.f;       sC[tid] = 0.f;       }
    }
    __syncthreads();
    int rowBase = blockIdx.x * 16;
    for (int i = tid; i < 16 * DIM; i += 256) {
        int r = i >> 6, c = i & 63;
        int gr = rowBase + r;
        float v = (gr < N_NODES) ? x[gr * DIM + c] : 0.f;
        sX[r][c] = fmaf(v, sA[c], sC[c]);
    }
    __syncthreads();

    int lane = tid & 63, w = tid >> 6;     // lane = output column, w = row group
    float b = sb[lane];
    float s0 = b, s1 = b, s2 = b, s3 = b;
    float n0 = 0.f, n1 = 0.f, n2 = 0.f, n3 = 0.f;
#pragma unroll
    for (int k = 0; k < DIM; ++k) {
        float ws = sWs[k * DIM + lane];
        float wn = sWn[k * DIM + lane];
        float x0 = sX[w * 4 + 0][k];
        float x1 = sX[w * 4 + 1][k];
        float x2 = sX[w * 4 + 2][k];
        float x3 = sX[w * 4 + 3][k];
        s0 = fmaf(x0, ws, s0); n0 = fmaf(x0, wn, n0);
        s1 = fmaf(x1, ws, s1); n1 = fmaf(x1, wn, n1);
        s2 = fmaf(x2, ws, s2); n2 = fmaf(x2, wn, n2);
        s3 = fmaf(x3, ws, s3); n3 = fmaf(x3, wn, n3);
    }
    int r0 = rowBase + w * 4;
    if (r0 + 0 < N_NODES) { xs[(r0 + 0) * DIM + lane] = s0; xn[(r0 + 0) * DIM + lane] = n0; }
    if (r0 + 1 < N_NODES) { xs[(r0 + 1) * DIM + lane] = s1; xn[(r0 + 1) * DIM + lane] = n1; }
    if (r0 + 2 < N_NODES) { xs[(r0 + 2) * DIM + lane] = s2; xn[(r0 + 2) * DIM + lane] = n2; }
    if (r0 + 3 < N_NODES) { xs[(r0 + 3) * DIM + lane] = s3; xn[(r0 + 3) * DIM + lane] = n3; }
}

// ---------------------------------------------------------------- aggregate: h = relu(xs + inv_deg * sum_{src} xn[src])
template<bool POOL>
__global__ void __launch_bounds__(256)
k_agg(const float* __restrict__ xs, const float* __restrict__ xn,
      const int* __restrict__ off, const int* __restrict__ csr_src,
      const float* __restrict__ inv_deg, const int* __restrict__ gind,
      float* __restrict__ h, float* __restrict__ pooled) {
    int lane = threadIdx.x & 63, w = threadIdx.x >> 6;
    int row = blockIdx.x * 4 + w;
    if (row >= N_NODES) return;
    int jb = off[row], je = off[row + 1];
    float acc = 0.f;
    int j = jb;
    for (; j + 4 <= je; j += 4) {
        int i0 = csr_src[j], i1 = csr_src[j + 1], i2 = csr_src[j + 2], i3 = csr_src[j + 3];
        float v0 = xn[i0 * DIM + lane];
        float v1 = xn[i1 * DIM + lane];
        float v2 = xn[i2 * DIM + lane];
        float v3 = xn[i3 * DIM + lane];
        acc += (v0 + v1) + (v2 + v3);
    }
    for (; j < je; ++j) acc += xn[csr_src[j] * DIM + lane];
    float val = fmaf(acc, inv_deg[row], xs[row * DIM + lane]);
    val = fmaxf(val, 0.f);
    h[row * DIM + lane] = val;
    if constexpr (POOL) {
        int g = gind[row];
        atomicAdd(&pooled[g * DIM + lane], val);
    }
}

// ---------------------------------------------------------------- BN stats (sum, sumsq per channel)
__global__ void __launch_bounds__(256)
k_stats(const float* __restrict__ h, float* __restrict__ sums) {
    int lane = threadIdx.x & 63, w = threadIdx.x >> 6;
    float s = 0.f, q = 0.f;
    for (int r = blockIdx.x * 4 + w; r < N_NODES; r += gridDim.x * 4) {
        float v = h[r * DIM + lane];
        s += v;
        q = fmaf(v, v, q);
    }
    __shared__ float sS[4][DIM], sQ[4][DIM];
    sS[w][lane] = s; sQ[w][lane] = q;
    __syncthreads();
    if (w == 0) {
        float ts = sS[0][lane] + sS[1][lane] + sS[2][lane] + sS[3][lane];
        float tq = sQ[0][lane] + sQ[1][lane] + sQ[2][lane] + sQ[3][lane];
        atomicAdd(&sums[lane], ts);
        atomicAdd(&sums[DIM + lane], tq);
    }
}

// ---------------------------------------------------------------- BN finalize: a = g*rsqrt(var+eps), c = be - mean*a
__global__ void k_bnfin(const float* __restrict__ sums, const float* __restrict__ g,
                        const float* __restrict__ be, float* __restrict__ a,
                        float* __restrict__ c) {
    int t = threadIdx.x;  // 64 threads
    float m = sums[t] * (1.0f / N_NODES);
    float q = sums[DIM + t] * (1.0f / N_NODES);
    float v = q - m * m;
    float inv = 1.0f / sqrtf(v + EPS);
    float av = g[t] * inv;
    a[t] = av;
    c[t] = be[t] - m * av;
}

// ---------------------------------------------------------------- MLP head (one block per graph)
__global__ void __launch_bounds__(128)
k_mlp(const float* __restrict__ pooled,
      const float* __restrict__ W1, const float* __restrict__ b1,
      const float* __restrict__ W2, const float* __restrict__ b2,
      const float* __restrict__ W3, const float* __restrict__ b3,
      float* __restrict__ out) {
    __shared__ float sp[64], s1[128], s2[64];
    int g = blockIdx.x, t = threadIdx.x;
    if (t < 64) sp[t] = pooled[g * 64 + t];
    __syncthreads();
    {
        float acc = b1[t];
#pragma unroll
        for (int k = 0; k < 64; ++k) acc = fmaf(sp[k], W1[k * 128 + t], acc);
        s1[t] = fmaxf(acc, 0.f);
    }
    __syncthreads();
    if (t < 64) {
        float acc = b2[t];
#pragma unroll
        for (int k = 0; k < 128; ++k) acc = fmaf(s1[k], W2[k * 64 + t], acc);
        s2[t] = fmaxf(acc, 0.f);
    }
    __syncthreads();
    if (t < 10) {
        float acc = b3[t];
#pragma unroll
        for (int k = 0; k < 64; ++k) acc = fmaf(s2[k], W3[k * 10 + t], acc);
        out[g * 10 + t] = acc;
    }
}

// ---------------------------------------------------------------- launch
extern "C" void kernel_launch(void* const* d_in, const int* in_sizes, int n_in,
                              void* d_out, int out_size, void* d_ws, size_t ws_size,
                              hipStream_t stream) {
    const float* x0   = (const float*)d_in[0];
    const int* e_src  = (const int*)d_in[1];
    const int* e_dst  = (const int*)d_in[2];
    const int* gind   = (const int*)d_in[3];
    // d_in[4] = labels (unused)
    const float* Ws1 = (const float*)d_in[5],  *Wn1 = (const float*)d_in[6],  *b1 = (const float*)d_in[7];
    const float* Ws2 = (const float*)d_in[8],  *Wn2 = (const float*)d_in[9],  *b2 = (const float*)d_in[10];
    const float* Ws3 = (const float*)d_in[11], *Wn3 = (const float*)d_in[12], *b3 = (const float*)d_in[13];
    const float* g2  = (const float*)d_in[14], *be2 = (const float*)d_in[15];
    const float* g3  = (const float*)d_in[16], *be3 = (const float*)d_in[17];
    const float* fcW1 = (const float*)d_in[18], *fcb1 = (const float*)d_in[19];
    const float* fcW2 = (const float*)d_in[20], *fcb2 = (const float*)d_in[21];
    const float* fcW3 = (const float*)d_in[22], *fcb3 = (const float*)d_in[23];
    float* out = (float*)d_out;

    char* p = (char*)d_ws;
    auto carve = [&](size_t bytes) { void* r = (void*)p; p += (bytes + 255) & ~(size_t)255; return r; };
    int*   deg     = (int*)  carve(N_NODES * 4);
    int*   off     = (int*)  carve((N_NODES + 1) * 4);
    int*   cursor  = (int*)  carve(N_NODES * 4);
    int*   csr_src = (int*)  carve(N_EDGES * 4);
    float* invd    = (float*)carve(N_NODES * 4);
    int*   bsum    = (int*)  carve(NSB * 4);
    int*   boff    = (int*)  carve((NSB + 1) * 4);
    float* sums2   = (float*)carve(128 * 4);
    float* sums3   = (float*)carve(128 * 4);
    float* a2      = (float*)carve(64 * 4);
    float* c2      = (float*)carve(64 * 4);
    float* a3      = (float*)carve(64 * 4);
    float* c3      = (float*)carve(64 * 4);
    float* pooled  = (float*)carve(NUM_GRAPHS * DIM * 4);
    float* bufH    = (float*)carve((size_t)N_NODES * DIM * 4);
    float* bufXS   = (float*)carve((size_t)N_NODES * DIM * 4);
    float* bufXN   = (float*)carve((size_t)N_NODES * DIM * 4);

    const int EB = (N_EDGES + 255) / 256;           // 3125
    const int GB = (N_NODES + 15) / 16;             // 3125 (gemm: 16 rows/block)
    const int AB = (N_NODES + 3) / 4;               // 12500 (agg: 4 rows/block)

    k_zero<<<(N_NODES + 255) / 256, 256, 0, stream>>>(deg, sums2, sums3, pooled);
    k_count<<<EB, 256, 0, stream>>>(e_dst, deg);
    k_scan1<<<NSB, SB, 0, stream>>>(deg, bsum);
    k_scan2<<<1, 64, 0, stream>>>(bsum, boff);
    k_scan3<<<NSB, SB, 0, stream>>>(deg, boff, off, cursor, invd);
    k_scatter<<<EB, 256, 0, stream>>>(e_src, e_dst, cursor, csr_src);

    // Layer 1 (no BN on input)
    k_gemm<false><<<GB, 256, 0, stream>>>(x0, Ws1, Wn1, b1, nullptr, nullptr, bufXS, bufXN);
    k_agg<false><<<AB, 256, 0, stream>>>(bufXS, bufXN, off, csr_src, invd, nullptr, bufH, nullptr);

    // BN2 stats + Layer 2
    k_stats<<<120, 256, 0, stream>>>(bufH, sums2);
    k_bnfin<<<1, 64, 0, stream>>>(sums2, g2, be2, a2, c2);
    k_gemm<true><<<GB, 256, 0, stream>>>(bufH, Ws2, Wn2, b2, a2, c2, bufXS, bufXN);
    k_agg<false><<<AB, 256, 0, stream>>>(bufXS, bufXN, off, csr_src, invd, nullptr, bufH, nullptr);

    // BN3 stats + Layer 3 (fused pooling)
    k_stats<<<120, 256, 0, stream>>>(bufH, sums3);
    k_bnfin<<<1, 64, 0, stream>>>(sums3, g3, be3, a3, c3);
    k_gemm<true><<<GB, 256, 0, stream>>>(bufH, Ws3, Wn3, b3, a3, c3, bufXS, bufXN);
    k_agg<true><<<AB, 256, 0, stream>>>(bufXS, bufXN, off, csr_src, invd, gind, bufH, pooled);

    // MLP head
    k_mlp<<<NUM_GRAPHS, 128, 0, stream>>>(pooled, fcW1, fcb1, fcW2, fcb2, fcW3, fcb3, out);
}

// Round 3
// 354.349 us; speedup vs baseline: 1.6904x; 1.3180x over previous
//
#include <hip/hip_runtime.h>

#define N_NODES   50000
#define N_EDGES   800000
#define DIM       64
#define NUM_GRAPHS 512
#define EPS       1e-5f

#define SB   1024
#define NSB  ((N_NODES + SB - 1) / SB)   // 49 scan blocks

// ---------------------------------------------------------------- zero init
__global__ void k_zero(int* __restrict__ deg, float* __restrict__ sums2,
                       float* __restrict__ sums3, float* __restrict__ pooled) {
    int i = blockIdx.x * 256 + threadIdx.x;
    if (i < N_NODES) deg[i] = 0;
    if (i < 128) { sums2[i] = 0.f; sums3[i] = 0.f; }
    if (i < NUM_GRAPHS * DIM) pooled[i] = 0.f;
}

// ---------------------------------------------------------------- degree count
__global__ void k_count(const int* __restrict__ dst, int* __restrict__ deg) {
    int i = blockIdx.x * 256 + threadIdx.x;
    if (i < N_EDGES) atomicAdd(&deg[dst[i]], 1);
}

// ---------------------------------------------------------------- scan phase 1: per-block sums
__global__ void __launch_bounds__(1024)
k_scan1(const int* __restrict__ deg, int* __restrict__ bsum) {
    __shared__ int red[16];
    int t = threadIdx.x;
    int i = blockIdx.x * SB + t;
    int v = (i < N_NODES) ? deg[i] : 0;
#pragma unroll
    for (int d = 32; d; d >>= 1) v += __shfl_down(v, d, 64);
    if ((t & 63) == 0) red[t >> 6] = v;
    __syncthreads();
    if (t < 16) {
        int s = red[t];
#pragma unroll
        for (int d = 8; d; d >>= 1) s += __shfl_down(s, d, 16);
        if (t == 0) bsum[blockIdx.x] = s;
    }
}

// ---------------------------------------------------------------- scan phase 2: scan of 49 block sums (1 wave)
__global__ void k_scan2(const int* __restrict__ bsum, int* __restrict__ boff) {
    int t = threadIdx.x;   // 64 threads
    int v = (t < NSB) ? bsum[t] : 0;
    int orig = v;
#pragma unroll
    for (int d = 1; d < 64; d <<= 1) {
        int u = __shfl_up(v, d, 64);
        if (t >= d) v += u;
    }
    if (t < NSB) boff[t] = v - orig;   // exclusive prefix
}

// ---------------------------------------------------------------- scan phase 3: full exclusive scan, write off/cursor/invd
__global__ void __launch_bounds__(1024)
k_scan3(const int* __restrict__ deg, const int* __restrict__ boff,
        int* __restrict__ off, int* __restrict__ cursor, float* __restrict__ invd) {
    __shared__ int wsum[16];
    int t = threadIdx.x, lane = t & 63, w = t >> 6;
    int i = blockIdx.x * SB + t;
    int d = (i < N_NODES) ? deg[i] : 0;
    int v = d;
#pragma unroll
    for (int s = 1; s < 64; s <<= 1) {
        int u = __shfl_up(v, s, 64);
        if (lane >= s) v += u;
    }
    if (lane == 63) wsum[w] = v;
    __syncthreads();
    if (t < 16) {
        int x = wsum[t];
#pragma unroll
        for (int s = 1; s < 16; s <<= 1) {
            int u = __shfl_up(x, s, 16);
            if (t >= s) x += u;
        }
        wsum[t] = x;   // inclusive across waves (lockstep within wave 0)
    }
    __syncthreads();
    if (i < N_NODES) {
        int ex = boff[blockIdx.x] + ((w > 0) ? wsum[w - 1] : 0) + v - d;
        off[i] = ex;
        cursor[i] = ex;
        invd[i] = 1.0f / (float)max(d, 1);
        if (i == N_NODES - 1) off[N_NODES] = ex + d;
    }
}

// ---------------------------------------------------------------- CSR scatter
__global__ void k_scatter(const int* __restrict__ src, const int* __restrict__ dst,
                          int* __restrict__ cursor, int* __restrict__ csr_src) {
    int i = blockIdx.x * 256 + threadIdx.x;
    if (i < N_EDGES) {
        int p = atomicAdd(&cursor[dst[i]], 1);
        csr_src[p] = src[i];
    }
}

// ---------------------------------------------------------------- dual GEMM, weights in registers
// xs = BN(x)@Ws + b ; xn = BN(x)@Wn.   32 rows/block, lane = out column.
#define GR 32   // rows per block
template<bool BN>
__global__ void __launch_bounds__(256, 3)
k_gemm(const float* __restrict__ x, const float* __restrict__ Ws,
       const float* __restrict__ Wn, const float* __restrict__ bias,
       const float* __restrict__ bn_a, const float* __restrict__ bn_c,
       float* __restrict__ xs, float* __restrict__ xn) {
    __shared__ float sX[GR][DIM];
    int tid = threadIdx.x;
    int lane = tid & 63, w = tid >> 6;

    // per-thread column of each weight matrix, fully unrolled -> registers
    float wsr[DIM], wnr[DIM];
#pragma unroll
    for (int k = 0; k < DIM; ++k) {
        wsr[k] = Ws[k * DIM + lane];
        wnr[k] = Wn[k * DIM + lane];
    }
    float bv = bias[lane];
    float aL = 1.f, cL = 0.f;
    if constexpr (BN) { aL = bn_a[lane]; cL = bn_c[lane]; }

    int rowBase = blockIdx.x * GR;
    // stage BN-folded rows (each wave stages rows w, w+4, ..., w+28; coalesced)
#pragma unroll
    for (int r = 0; r < GR / 4; ++r) {
        int row = r * 4 + w;
        int gr = rowBase + row;
        float v = (gr < N_NODES) ? x[gr * DIM + lane] : 0.f;
        sX[row][lane] = fmaf(v, aL, cL);
    }
    __syncthreads();

    // wave w computes rows [w*8, w*8+8)
#pragma unroll
    for (int r = 0; r < 8; ++r) {
        int row = w * 8 + r;
        float s = bv, n = 0.f;
#pragma unroll
        for (int kg = 0; kg < DIM / 4; ++kg) {
            float4 xv = *reinterpret_cast<const float4*>(&sX[row][kg * 4]);
            s = fmaf(xv.x, wsr[kg * 4 + 0], s); n = fmaf(xv.x, wnr[kg * 4 + 0], n);
            s = fmaf(xv.y, wsr[kg * 4 + 1], s); n = fmaf(xv.y, wnr[kg * 4 + 1], n);
            s = fmaf(xv.z, wsr[kg * 4 + 2], s); n = fmaf(xv.z, wnr[kg * 4 + 2], n);
            s = fmaf(xv.w, wsr[kg * 4 + 3], s); n = fmaf(xv.w, wnr[kg * 4 + 3], n);
        }
        int grow = rowBase + row;
        if (grow < N_NODES) {
            xs[grow * DIM + lane] = s;
            xn[grow * DIM + lane] = n;
        }
    }
}

// ---------------------------------------------------------------- aggregate: h = relu(xs + inv_deg * sum_{src} xn[src])
template<bool POOL>
__global__ void __launch_bounds__(256)
k_agg(const float* __restrict__ xs, const float* __restrict__ xn,
      const int* __restrict__ off, const int* __restrict__ csr_src,
      const float* __restrict__ inv_deg, const int* __restrict__ gind,
      float* __restrict__ h, float* __restrict__ pooled) {
    int lane = threadIdx.x & 63, w = threadIdx.x >> 6;
    int row = blockIdx.x * 4 + w;
    if (row >= N_NODES) return;
    int jb = off[row], je = off[row + 1];
    float acc = 0.f;
    int j = jb;
    for (; j + 4 <= je; j += 4) {
        int i0 = csr_src[j], i1 = csr_src[j + 1], i2 = csr_src[j + 2], i3 = csr_src[j + 3];
        float v0 = xn[i0 * DIM + lane];
        float v1 = xn[i1 * DIM + lane];
        float v2 = xn[i2 * DIM + lane];
        float v3 = xn[i3 * DIM + lane];
        acc += (v0 + v1) + (v2 + v3);
    }
    for (; j < je; ++j) acc += xn[csr_src[j] * DIM + lane];
    float val = fmaf(acc, inv_deg[row], xs[row * DIM + lane]);
    val = fmaxf(val, 0.f);
    h[row * DIM + lane] = val;
    if constexpr (POOL) {
        int g = gind[row];
        atomicAdd(&pooled[g * DIM + lane], val);
    }
}

// ---------------------------------------------------------------- BN stats (sum, sumsq per channel)
__global__ void __launch_bounds__(256)
k_stats(const float* __restrict__ h, float* __restrict__ sums) {
    int lane = threadIdx.x & 63, w = threadIdx.x >> 6;
    float s = 0.f, q = 0.f;
    for (int r = blockIdx.x * 4 + w; r < N_NODES; r += gridDim.x * 4) {
        float v = h[r * DIM + lane];
        s += v;
        q = fmaf(v, v, q);
    }
    __shared__ float sS[4][DIM], sQ[4][DIM];
    sS[w][lane] = s; sQ[w][lane] = q;
    __syncthreads();
    if (w == 0) {
        float ts = sS[0][lane] + sS[1][lane] + sS[2][lane] + sS[3][lane];
        float tq = sQ[0][lane] + sQ[1][lane] + sQ[2][lane] + sQ[3][lane];
        atomicAdd(&sums[lane], ts);
        atomicAdd(&sums[DIM + lane], tq);
    }
}

// ---------------------------------------------------------------- BN finalize: a = g*rsqrt(var+eps), c = be - mean*a
__global__ void k_bnfin(const float* __restrict__ sums, const float* __restrict__ g,
                        const float* __restrict__ be, float* __restrict__ a,
                        float* __restrict__ c) {
    int t = threadIdx.x;  // 64 threads
    float m = sums[t] * (1.0f / N_NODES);
    float q = sums[DIM + t] * (1.0f / N_NODES);
    float v = q - m * m;
    float inv = 1.0f / sqrtf(v + EPS);
    float av = g[t] * inv;
    a[t] = av;
    c[t] = be[t] - m * av;
}

// ---------------------------------------------------------------- MLP head (one block per graph)
__global__ void __launch_bounds__(128)
k_mlp(const float* __restrict__ pooled,
      const float* __restrict__ W1, const float* __restrict__ b1,
      const float* __restrict__ W2, const float* __restrict__ b2,
      const float* __restrict__ W3, const float* __restrict__ b3,
      float* __restrict__ out) {
    __shared__ float sp[64], s1[128], s2[64];
    int g = blockIdx.x, t = threadIdx.x;
    if (t < 64) sp[t] = pooled[g * 64 + t];
    __syncthreads();
    {
        float acc = b1[t];
#pragma unroll
        for (int k = 0; k < 64; ++k) acc = fmaf(sp[k], W1[k * 128 + t], acc);
        s1[t] = fmaxf(acc, 0.f);
    }
    __syncthreads();
    if (t < 64) {
        float acc = b2[t];
#pragma unroll
        for (int k = 0; k < 128; ++k) acc = fmaf(s1[k], W2[k * 64 + t], acc);
        s2[t] = fmaxf(acc, 0.f);
    }
    __syncthreads();
    if (t < 10) {
        float acc = b3[t];
#pragma unroll
        for (int k = 0; k < 64; ++k) acc = fmaf(s2[k], W3[k * 10 + t], acc);
        out[g * 10 + t] = acc;
    }
}

// ---------------------------------------------------------------- launch
extern "C" void kernel_launch(void* const* d_in, const int* in_sizes, int n_in,
                              void* d_out, int out_size, void* d_ws, size_t ws_size,
                              hipStream_t stream) {
    const float* x0   = (const float*)d_in[0];
    const int* e_src  = (const int*)d_in[1];
    const int* e_dst  = (const int*)d_in[2];
    const int* gind   = (const int*)d_in[3];
    // d_in[4] = labels (unused)
    const float* Ws1 = (const float*)d_in[5],  *Wn1 = (const float*)d_in[6],  *b1 = (const float*)d_in[7];
    const float* Ws2 = (const float*)d_in[8],  *Wn2 = (const float*)d_in[9],  *b2 = (const float*)d_in[10];
    const float* Ws3 = (const float*)d_in[11], *Wn3 = (const float*)d_in[12], *b3 = (const float*)d_in[13];
    const float* g2  = (const float*)d_in[14], *be2 = (const float*)d_in[15];
    const float* g3  = (const float*)d_in[16], *be3 = (const float*)d_in[17];
    const float* fcW1 = (const float*)d_in[18], *fcb1 = (const float*)d_in[19];
    const float* fcW2 = (const float*)d_in[20], *fcb2 = (const float*)d_in[21];
    const float* fcW3 = (const float*)d_in[22], *fcb3 = (const float*)d_in[23];
    float* out = (float*)d_out;

    char* p = (char*)d_ws;
    auto carve = [&](size_t bytes) { void* r = (void*)p; p += (bytes + 255) & ~(size_t)255; return r; };
    int*   deg     = (int*)  carve(N_NODES * 4);
    int*   off     = (int*)  carve((N_NODES + 1) * 4);
    int*   cursor  = (int*)  carve(N_NODES * 4);
    int*   csr_src = (int*)  carve(N_EDGES * 4);
    float* invd    = (float*)carve(N_NODES * 4);
    int*   bsum    = (int*)  carve(NSB * 4);
    int*   boff    = (int*)  carve((NSB + 1) * 4);
    float* sums2   = (float*)carve(128 * 4);
    float* sums3   = (float*)carve(128 * 4);
    float* a2      = (float*)carve(64 * 4);
    float* c2      = (float*)carve(64 * 4);
    float* a3      = (float*)carve(64 * 4);
    float* c3      = (float*)carve(64 * 4);
    float* pooled  = (float*)carve(NUM_GRAPHS * DIM * 4);
    float* bufH    = (float*)carve((size_t)N_NODES * DIM * 4);
    float* bufXS   = (float*)carve((size_t)N_NODES * DIM * 4);
    float* bufXN   = (float*)carve((size_t)N_NODES * DIM * 4);

    const int EB = (N_EDGES + 255) / 256;           // 3125
    const int GB = (N_NODES + GR - 1) / GR;         // 1563 (gemm: 32 rows/block)
    const int AB = (N_NODES + 3) / 4;               // 12500 (agg: 4 rows/block)

    k_zero<<<(N_NODES + 255) / 256, 256, 0, stream>>>(deg, sums2, sums3, pooled);
    k_count<<<EB, 256, 0, stream>>>(e_dst, deg);
    k_scan1<<<NSB, SB, 0, stream>>>(deg, bsum);
    k_scan2<<<1, 64, 0, stream>>>(bsum, boff);
    k_scan3<<<NSB, SB, 0, stream>>>(deg, boff, off, cursor, invd);
    k_scatter<<<EB, 256, 0, stream>>>(e_src, e_dst, cursor, csr_src);

    // Layer 1 (no BN on input)
    k_gemm<false><<<GB, 256, 0, stream>>>(x0, Ws1, Wn1, b1, nullptr, nullptr, bufXS, bufXN);
    k_agg<false><<<AB, 256, 0, stream>>>(bufXS, bufXN, off, csr_src, invd, nullptr, bufH, nullptr);

    // BN2 stats + Layer 2
    k_stats<<<120, 256, 0, stream>>>(bufH, sums2);
    k_bnfin<<<1, 64, 0, stream>>>(sums2, g2, be2, a2, c2);
    k_gemm<true><<<GB, 256, 0, stream>>>(bufH, Ws2, Wn2, b2, a2, c2, bufXS, bufXN);
    k_agg<false><<<AB, 256, 0, stream>>>(bufXS, bufXN, off, csr_src, invd, nullptr, bufH, nullptr);

    // BN3 stats + Layer 3 (fused pooling)
    k_stats<<<120, 256, 0, stream>>>(bufH, sums3);
    k_bnfin<<<1, 64, 0, stream>>>(sums3, g3, be3, a3, c3);
    k_gemm<true><<<GB, 256, 0, stream>>>(bufH, Ws3, Wn3, b3, a3, c3, bufXS, bufXN);
    k_agg<true><<<AB, 256, 0, stream>>>(bufXS, bufXN, off, csr_src, invd, gind, bufH, pooled);

    // MLP head
    k_mlp<<<NUM_GRAPHS, 128, 0, stream>>>(pooled, fcW1, fcb1, fcW2, fcb2, fcW3, fcb3, out);
}